// Round 5
// baseline (295.368 us; speedup 1.0000x reference)
//
#include <hip/hip_runtime.h>

// ---------------------------------------------------------------------------
// RelGraphConv x3 + action mask, MI355X (gfx950) — round 5
// R4 post-mortem: fused mega1 (gemm1+scatter) at 89us was occupancy-starved —
// scatter blocks reserved 42.5KB LDS they never used (3 blocks/CU). Split:
//  * scatter standalone: no LDS, 4-edge ILP, all blocks co-resident
//  * gemm1 standalone: bf16 xs staging (LDS 34.1KB -> 4 blocks/CU)
//  * agg gathers unrolled 8 (2 latency rounds for deg~16 instead of 4)
// ---------------------------------------------------------------------------

#define STRIDE 64  // bucket capacity; P(deg>=64) astronomically small @ Poisson(16)

typedef unsigned short ushortT;

__device__ inline ushortT f2bf(float f) {
    union { float f; unsigned u; } v; v.f = f;
    unsigned r = v.u + 0x7FFFu + ((v.u >> 16) & 1u);   // RNE
    return (ushortT)(r >> 16);
}
__device__ inline float bf2f(ushortT h) {
    union { unsigned u; float f; } v; v.u = ((unsigned)h) << 16;
    return v.f;
}

__device__ inline void atomicMinF(float* addr, float v) {
    if (v >= 0.f) atomicMin((int*)addr, __float_as_int(v));
    else          atomicMax((unsigned int*)addr, __float_as_uint(v));
}

// ---- scatter: standalone, 1024 edges/block, 4 per thread (batched atomics) -
__global__ __launch_bounds__(256) void scatter_kernel(
    const int* __restrict__ src, const int* __restrict__ dst,
    const int* __restrict__ et, int* __restrict__ cnt, int* __restrict__ eidx,
    int N, int E) {
    int e0 = (int)blockIdx.x * 1024 + (int)threadIdx.x;
    int e1 = e0 + 256, e2 = e0 + 512, e3 = e0 + 768;
    bool a0 = e0 < E, a1 = e1 < E, a2 = e2 < E, a3 = e3 < E;
    int d0 = a0 ? dst[e0] : 0, d1 = a1 ? dst[e1] : 0;
    int d2 = a2 ? dst[e2] : 0, d3 = a3 ? dst[e3] : 0;
    int v0 = a0 ? (et[e0] * N + src[e0]) : 0;
    int v1 = a1 ? (et[e1] * N + src[e1]) : 0;
    int v2 = a2 ? (et[e2] * N + src[e2]) : 0;
    int v3 = a3 ? (et[e3] * N + src[e3]) : 0;
    int p0 = 0, p1 = 0, p2 = 0, p3 = 0;
    if (a0) p0 = atomicAdd(&cnt[d0], 1);
    if (a1) p1 = atomicAdd(&cnt[d1], 1);
    if (a2) p2 = atomicAdd(&cnt[d2], 1);
    if (a3) p3 = atomicAdd(&cnt[d3], 1);
    if (a0 && p0 < STRIDE) eidx[(size_t)d0 * STRIDE + p0] = v0;
    if (a1 && p1 < STRIDE) eidx[(size_t)d1 * STRIDE + p1] = v1;
    if (a2 && p2 < STRIDE) eidx[(size_t)d2 * STRIDE + p2] = v2;
    if (a3 && p3 < STRIDE) eidx[(size_t)d3 * STRIDE + p3] = v3;
}

// ---- gemm1: 64-node tile, 3 mats (W0, W1, Wloop), K=128, bf16 LDS ----------
__global__ __launch_bounds__(256) void gemm1_kernel(
    const float* __restrict__ x, const float* __restrict__ W1,
    const float* __restrict__ loop1, const float* __restrict__ b1,
    ushortT* __restrict__ hrelb, ushortT* __restrict__ H1b, int N) {
    __shared__ ushortT xsb[64][64];       // [k][rotated node], rotation = k&~3
    __shared__ ushortT wsb[3][64][68];    // bf16 weight tiles
    const int nbase = (int)blockIdx.x * 64;
    const int t = (int)threadIdx.x;
    const int tx = t & 15, ty = t >> 4;

    float acc[3][4][4];
#pragma unroll
    for (int m = 0; m < 3; ++m)
#pragma unroll
        for (int j = 0; j < 4; ++j)
#pragma unroll
            for (int i = 0; i < 4; ++i) acc[m][j][i] = 0.f;

    for (int kt = 0; kt < 2; ++kt) {
        // stage x tile bf16, transposed+rotated: xsb[k][(node + (k&~3)) & 63]
#pragma unroll
        for (int j = 0; j < 4; ++j) {
            int i = t + j * 256;
            int node = i >> 4;
            int kk4 = (i & 15) * 4;
            int n = nbase + node;
            float4 g = make_float4(0.f, 0.f, 0.f, 0.f);
            if (n < N) g = *(const float4*)&x[(size_t)n * 128 + kt * 64 + kk4];
            int pc = (node + kk4) & 63;
            xsb[kk4 + 0][pc] = f2bf(g.x);
            xsb[kk4 + 1][pc] = f2bf(g.y);
            xsb[kk4 + 2][pc] = f2bf(g.z);
            xsb[kk4 + 3][pc] = f2bf(g.w);
        }
        // stage 3 bf16 weight tiles: 12 float4 slots per thread
#pragma unroll
        for (int j = 0; j < 12; ++j) {
            int i = t + j * 256;
            int mat = i >> 10;
            int rc = i & 1023;
            int kk = rc >> 4;
            int c4 = (rc & 15) * 4;
            const float* Wm = (mat < 2) ? (W1 + ((size_t)mat * 128 + kt * 64 + kk) * 64 + c4)
                                        : (loop1 + ((size_t)kt * 64 + kk) * 64 + c4);
            float4 g = *(const float4*)Wm;
            ushort4 o;
            o.x = f2bf(g.x); o.y = f2bf(g.y); o.z = f2bf(g.z); o.w = f2bf(g.w);
            *(ushort4*)&wsb[mat][kk][c4] = o;
        }
        __syncthreads();

#pragma unroll 4
        for (int kk = 0; kk < 64; ++kk) {
            int kb = kk & ~3;
            ushort4 au = *(const ushort4*)&xsb[kk][(ty * 4 + kb) & 63];
            float ax = bf2f(au.x), ay = bf2f(au.y), az = bf2f(au.z), aw = bf2f(au.w);
#pragma unroll
            for (int m = 0; m < 3; ++m) {
                ushort4 wu = *(const ushort4*)&wsb[m][kk][tx * 4];
                float w0 = bf2f(wu.x), w1 = bf2f(wu.y), w2 = bf2f(wu.z), w3 = bf2f(wu.w);
                acc[m][0][0] += ax * w0; acc[m][0][1] += ax * w1; acc[m][0][2] += ax * w2; acc[m][0][3] += ax * w3;
                acc[m][1][0] += ay * w0; acc[m][1][1] += ay * w1; acc[m][1][2] += ay * w2; acc[m][1][3] += ay * w3;
                acc[m][2][0] += az * w0; acc[m][2][1] += az * w1; acc[m][2][2] += az * w2; acc[m][2][3] += az * w3;
                acc[m][3][0] += aw * w0; acc[m][3][1] += aw * w1; acc[m][3][2] += aw * w2; acc[m][3][3] += aw * w3;
            }
        }
        __syncthreads();
    }

    float b0 = b1[tx * 4 + 0], bb1 = b1[tx * 4 + 1], b2v = b1[tx * 4 + 2], b3v = b1[tx * 4 + 3];
#pragma unroll
    for (int j = 0; j < 4; ++j) {
        int n = nbase + ty * 4 + j;
        if (n < N) {
#pragma unroll
            for (int m = 0; m < 2; ++m) {
                ushort4 o;
                o.x = f2bf(acc[m][j][0]); o.y = f2bf(acc[m][j][1]);
                o.z = f2bf(acc[m][j][2]); o.w = f2bf(acc[m][j][3]);
                *(ushort4*)&hrelb[((size_t)m * N + n) * 64 + tx * 4] = o;
            }
            ushort4 h;
            h.x = f2bf(acc[2][j][0] + b0);  h.y = f2bf(acc[2][j][1] + bb1);
            h.z = f2bf(acc[2][j][2] + b2v); h.w = f2bf(acc[2][j][3] + b3v);
            *(ushort4*)&H1b[(size_t)n * 64 + tx * 4] = h;
        }
    }
}

// ---- agg1: wave per node, lane = channel, bf16 gather (8 outstanding) ------
__global__ void agg1_kernel(const ushortT* __restrict__ hrelb, const int* __restrict__ eidx,
                            const int* __restrict__ cnt, ushortT* __restrict__ H1b, int N) {
    int node = (int)blockIdx.x * 4 + ((int)threadIdx.x >> 6);
    if (node >= N) return;
    int lane = (int)threadIdx.x & 63;
    int deg = min(cnt[node], STRIDE);
    int my = (lane < deg) ? eidx[(size_t)node * STRIDE + lane] : 0;
    float acc = bf2f(H1b[(size_t)node * 64 + lane]);
    int j = 0;
    for (; j + 7 < deg; j += 8) {
        int id[8];
        float v[8];
#pragma unroll
        for (int q = 0; q < 8; ++q) id[q] = __shfl(my, j + q, 64);
#pragma unroll
        for (int q = 0; q < 8; ++q) v[q] = bf2f(hrelb[(size_t)id[q] * 64 + lane]);
        acc += ((v[0] + v[1]) + (v[2] + v[3])) + ((v[4] + v[5]) + (v[6] + v[7]));
    }
    for (; j < deg; ++j)
        acc += bf2f(hrelb[(size_t)__shfl(my, j, 64) * 64 + lane]);
    H1b[(size_t)node * 64 + lane] = f2bf(fmaxf(acc, 0.f));
}

// ---- gemm2: 64-node tile, 3 mats, K=64, bf16 LDS ---------------------------
__global__ __launch_bounds__(256) void gemm2_kernel(
    const ushortT* __restrict__ H1b,
    const float* __restrict__ W2, const float* __restrict__ loop2,
    const float* __restrict__ b2,
    ushortT* __restrict__ hrel2b, float* __restrict__ H2, int N) {
    __shared__ ushortT xsb[64][66];       // [node][k], 33-word row stride
    __shared__ ushortT wsb[3][64][68];
    const int t = (int)threadIdx.x;
    const int nbase = (int)blockIdx.x * 64;

#pragma unroll
    for (int j = 0; j < 12; ++j) {
        int i = t + j * 256;
        int mat = i >> 10;
        int rc = i & 1023;
        int kk = rc >> 4;
        int c4 = (rc & 15) * 4;
        const float* Wm = (mat < 2) ? (W2 + ((size_t)mat * 64 + kk) * 64 + c4)
                                    : (loop2 + (size_t)kk * 64 + c4);
        float4 g = *(const float4*)Wm;
        ushort4 o;
        o.x = f2bf(g.x); o.y = f2bf(g.y); o.z = f2bf(g.z); o.w = f2bf(g.w);
        *(ushort4*)&wsb[mat][kk][c4] = o;
    }
#pragma unroll
    for (int j = 0; j < 4; ++j) {
        int i = t + j * 256;
        int node = i >> 4;
        int k4 = (i & 15) * 4;
        int n = nbase + node;
        ushort4 g = make_ushort4(0, 0, 0, 0);
        if (n < N) g = *(const ushort4*)&H1b[(size_t)n * 64 + k4];
        *(ushort4*)&xsb[node][k4] = g;
    }
    __syncthreads();

    const int tx = t & 15, ty = t >> 4;
    float acc2[3][4][4];
#pragma unroll
    for (int m = 0; m < 3; ++m)
#pragma unroll
        for (int j = 0; j < 4; ++j)
#pragma unroll
            for (int i = 0; i < 4; ++i) acc2[m][j][i] = 0.f;

#pragma unroll 4
    for (int kk = 0; kk < 64; ++kk) {
        float a0 = bf2f(xsb[ty * 4 + 0][kk]);
        float a1 = bf2f(xsb[ty * 4 + 1][kk]);
        float a2 = bf2f(xsb[ty * 4 + 2][kk]);
        float a3 = bf2f(xsb[ty * 4 + 3][kk]);
#pragma unroll
        for (int m = 0; m < 3; ++m) {
            ushort4 wu = *(const ushort4*)&wsb[m][kk][tx * 4];
            float w0 = bf2f(wu.x), w1 = bf2f(wu.y), w2 = bf2f(wu.z), w3 = bf2f(wu.w);
            acc2[m][0][0] += a0 * w0; acc2[m][0][1] += a0 * w1; acc2[m][0][2] += a0 * w2; acc2[m][0][3] += a0 * w3;
            acc2[m][1][0] += a1 * w0; acc2[m][1][1] += a1 * w1; acc2[m][1][2] += a1 * w2; acc2[m][1][3] += a1 * w3;
            acc2[m][2][0] += a2 * w0; acc2[m][2][1] += a2 * w1; acc2[m][2][2] += a2 * w2; acc2[m][2][3] += a2 * w3;
            acc2[m][3][0] += a3 * w0; acc2[m][3][1] += a3 * w1; acc2[m][3][2] += a3 * w2; acc2[m][3][3] += a3 * w3;
        }
    }

    float b0 = b2[tx * 4 + 0], bb1 = b2[tx * 4 + 1], b2v = b2[tx * 4 + 2], b3v = b2[tx * 4 + 3];
#pragma unroll
    for (int j = 0; j < 4; ++j) {
        int n = nbase + ty * 4 + j;
        if (n < N) {
#pragma unroll
            for (int m = 0; m < 2; ++m) {
                ushort4 o;
                o.x = f2bf(acc2[m][j][0]); o.y = f2bf(acc2[m][j][1]);
                o.z = f2bf(acc2[m][j][2]); o.w = f2bf(acc2[m][j][3]);
                *(ushort4*)&hrel2b[((size_t)m * N + n) * 64 + tx * 4] = o;
            }
            float4 h = make_float4(acc2[2][j][0] + b0, acc2[2][j][1] + bb1,
                                   acc2[2][j][2] + b2v, acc2[2][j][3] + b3v);
            *(float4*)&H2[(size_t)n * 64 + tx * 4] = h;
        }
    }
}

// ---- K3: fused agg(layer2) + gemm(layer3, out=2), wave per node ------------
__global__ void k3_kernel(const ushortT* __restrict__ hrel2b, const float* __restrict__ H2,
                          const int* __restrict__ eidx, const int* __restrict__ cnt,
                          const float* __restrict__ W3, const float* __restrict__ loop3,
                          const float* __restrict__ b3,
                          float* __restrict__ hrel3, float* __restrict__ H3, int N) {
    int node = (int)blockIdx.x * 4 + ((int)threadIdx.x >> 6);
    if (node >= N) return;
    int lane = (int)threadIdx.x & 63;
    int deg = min(cnt[node], STRIDE);
    int my = (lane < deg) ? eidx[(size_t)node * STRIDE + lane] : 0;
    float acc = H2[(size_t)node * 64 + lane];
    int j = 0;
    for (; j + 7 < deg; j += 8) {
        int id[8];
        float v[8];
#pragma unroll
        for (int q = 0; q < 8; ++q) id[q] = __shfl(my, j + q, 64);
#pragma unroll
        for (int q = 0; q < 8; ++q) v[q] = bf2f(hrel2b[(size_t)id[q] * 64 + lane]);
        acc += ((v[0] + v[1]) + (v[2] + v[3])) + ((v[4] + v[5]) + (v[6] + v[7]));
    }
    for (; j < deg; ++j)
        acc += bf2f(hrel2b[(size_t)__shfl(my, j, 64) * 64 + lane]);
    float xk = fmaxf(acc, 0.f);  // relu(layer-2 out), lane = k
    float p[6];
    p[0] = xk * W3[lane * 2 + 0];
    p[1] = xk * W3[lane * 2 + 1];
    p[2] = xk * W3[(64 + lane) * 2 + 0];
    p[3] = xk * W3[(64 + lane) * 2 + 1];
    p[4] = xk * loop3[lane * 2 + 0];
    p[5] = xk * loop3[lane * 2 + 1];
#pragma unroll
    for (int m = 32; m >= 1; m >>= 1) {
#pragma unroll
        for (int q = 0; q < 6; ++q) p[q] += __shfl_xor(p[q], m, 64);
    }
    if (lane == 0) {
        hrel3[(size_t)node * 2 + 0] = p[0];
        hrel3[(size_t)node * 2 + 1] = p[1];
        hrel3[((size_t)N + node) * 2 + 0] = p[2];
        hrel3[((size_t)N + node) * 2 + 1] = p[3];
        H3[(size_t)node * 2 + 0] = p[4] + b3[0];
        H3[(size_t)node * 2 + 1] = p[5] + b3[1];
    }
}

// ---- K4: layer-3 aggregation + global min ----------------------------------
__global__ void agg3min_kernel(const float* __restrict__ hrel3, const int* __restrict__ eidx,
                               const int* __restrict__ cnt, float* __restrict__ H3,
                               float* __restrict__ minval, int N) {
    int n = (int)blockIdx.x * 256 + (int)threadIdx.x;
    float v = 3.4e38f;
    if (n < N) {
        float a0 = H3[n * 2 + 0], a1 = H3[n * 2 + 1];
        int deg = min(cnt[n], STRIDE);
        const int* row = &eidx[(size_t)n * STRIDE];
        int j = 0;
        for (; j + 3 < deg; j += 4) {
            int i0 = row[j], i1 = row[j + 1], i2 = row[j + 2], i3 = row[j + 3];
            float2 q0 = *(const float2*)&hrel3[(size_t)i0 * 2];
            float2 q1 = *(const float2*)&hrel3[(size_t)i1 * 2];
            float2 q2 = *(const float2*)&hrel3[(size_t)i2 * 2];
            float2 q3 = *(const float2*)&hrel3[(size_t)i3 * 2];
            a0 += (q0.x + q1.x) + (q2.x + q3.x);
            a1 += (q0.y + q1.y) + (q2.y + q3.y);
        }
        for (; j < deg; ++j) {
            float2 q = *(const float2*)&hrel3[(size_t)row[j] * 2];
            a0 += q.x; a1 += q.y;
        }
        H3[n * 2 + 0] = a0;
        H3[n * 2 + 1] = a1;
        v = fminf(a0, a1);
    }
#pragma unroll
    for (int m = 32; m >= 1; m >>= 1) v = fminf(v, __shfl_xor(v, m, 64));
    __shared__ float s[4];
    if ((threadIdx.x & 63) == 0) s[threadIdx.x >> 6] = v;
    __syncthreads();
    if (threadIdx.x == 0)
        atomicMinF(minval, fminf(fminf(s[0], s[1]), fminf(s[2], s[3])));
}

__global__ void mask_kernel(const float* __restrict__ H3, const float* __restrict__ minval,
                            const int* __restrict__ cs, const int* __restrict__ ms,
                            float* __restrict__ out, int N) {
    int n = (int)blockIdx.x * 256 + (int)threadIdx.x;
    if (n >= N) return;
    float m = minval[0] - 1.0f;
    bool up = cs[n] >= ms[n] - 1;
    bool lo = cs[n] == 0;
    out[n * 2 + 0] = up ? m : H3[n * 2 + 0];
    out[n * 2 + 1] = lo ? m : H3[n * 2 + 1];
}

// ---------------------------------------------------------------------------
extern "C" void kernel_launch(void* const* d_in, const int* in_sizes, int n_in,
                              void* d_out, int out_size, void* d_ws, size_t ws_size,
                              hipStream_t stream) {
    const float* x     = (const float*)d_in[0];
    const int* src     = (const int*)d_in[1];
    const int* dst     = (const int*)d_in[2];
    const int* etypes  = (const int*)d_in[3];
    const int* cellsz  = (const int*)d_in[4];
    const int* maxsz   = (const int*)d_in[5];
    const float* W1    = (const float*)d_in[6];
    const float* loop1 = (const float*)d_in[7];
    const float* b1    = (const float*)d_in[8];
    const float* W2    = (const float*)d_in[9];
    const float* loop2 = (const float*)d_in[10];
    const float* b2    = (const float*)d_in[11];
    const float* W3    = (const float*)d_in[12];
    const float* loop3 = (const float*)d_in[13];
    const float* b3    = (const float*)d_in[14];
    float* out = (float*)d_out;

    const int N = in_sizes[0] / 128;  // 50000
    const int E = in_sizes[1];        // 800000

    char* p = (char*)d_ws;
    auto alloc = [&](size_t bytes) -> void* {
        void* r = (void*)p;
        p += ((bytes + 255) / 256) * 256;
        return r;
    };
    ushortT* hrelb  = (ushortT*)alloc((size_t)2 * N * 64 * 2);  // 12.8 MB bf16
    ushortT* H1b    = (ushortT*)alloc((size_t)N * 64 * 2);      //  6.4 MB bf16
    ushortT* hrel2b = (ushortT*)alloc((size_t)2 * N * 64 * 2);  // 12.8 MB bf16
    float* H2       = (float*)alloc((size_t)N * 64 * 4);        // 12.8 MB
    float* hrel3    = (float*)alloc((size_t)2 * N * 2 * 4);
    float* H3       = (float*)alloc((size_t)N * 2 * 4);
    int* cnt        = (int*)alloc((size_t)N * 4);
    int* eidx       = (int*)alloc((size_t)N * STRIDE * 4);      // 12.8 MB
    float* minval   = (float*)alloc(4);
    (void)ws_size; (void)n_in; (void)out_size;

    const int NB_N   = (N + 255) / 256;      // 196
    const int NTILES = (N + 63) / 64;        // 782
    const int NB_W   = (N + 3) / 4;          // 12500
    const int NB_SC  = (E + 1023) / 1024;    // 782

    hipMemsetAsync(cnt, 0, (size_t)N * 4, stream);
    hipMemsetAsync(minval, 0x7f, 4, stream);  // 0x7f7f7f7f = 3.39e38

    // bucket scatter (all blocks co-resident: no LDS, low VGPR, 4-edge ILP)
    scatter_kernel<<<NB_SC, 256, 0, stream>>>(src, dst, etypes, cnt, eidx, N, E);

    // layer-1 GEMM (3 mats/block, bf16 LDS)
    gemm1_kernel<<<NTILES, 256, 0, stream>>>(x, W1, loop1, b1, hrelb, H1b, N);

    // layer-1 aggregation: wave per node
    agg1_kernel<<<NB_W, 256, 0, stream>>>(hrelb, eidx, cnt, H1b, N);

    // layer-2 GEMM
    gemm2_kernel<<<NTILES, 256, 0, stream>>>(H1b, W2, loop2, b2, hrel2b, H2, N);

    // fused agg(layer2) + gemm(layer3)
    k3_kernel<<<NB_W, 256, 0, stream>>>(hrel2b, H2, eidx, cnt, W3, loop3, b3,
                                        hrel3, H3, N);

    // layer-3 aggregation + global min, then mask
    agg3min_kernel<<<NB_N, 256, 0, stream>>>(hrel3, eidx, cnt, H3, minval, N);
    mask_kernel<<<NB_N, 256, 0, stream>>>(H3, minval, cellsz, maxsz, out, N);
}

// Round 6
// 258.048 us; speedup vs baseline: 1.1446x; 1.1446x over previous
//
#include <hip/hip_runtime.h>

// ---------------------------------------------------------------------------
// RelGraphConv x3 + action mask, MI355X (gfx950) — round 6
// R5 post-mortem: VALU GEMM was grid-starved (782 blocks) + cvt-heavy, 62us.
// This round: MFMA 16x16x32_bf16 GEMMs, LDS-free.
//  * pack kernel: W1/W2 -> fragment-ordered bf16 (B-frag = coalesced 16B/lane)
//  * gemm1/gemm2: wave = 16 nodes x 192 cols, A-frags from global, 48/24 MFMA
//  * pack blocks fused into scatter launch (both lean, no LDS)
//  * H2 now bf16 (k3 adapted)
// ---------------------------------------------------------------------------

#define STRIDE 64  // bucket capacity; P(deg>=64) astronomically small @ Poisson(16)

typedef unsigned short ushortT;
typedef __attribute__((ext_vector_type(8))) short short8;   // 8 bf16 (4 VGPRs)
typedef __attribute__((ext_vector_type(4))) float f32x4;    // MFMA C/D

__device__ inline ushortT f2bf(float f) {
    union { float f; unsigned u; } v; v.f = f;
    unsigned r = v.u + 0x7FFFu + ((v.u >> 16) & 1u);   // RNE
    return (ushortT)(r >> 16);
}
__device__ inline float bf2f(ushortT h) {
    union { unsigned u; float f; } v; v.u = ((unsigned)h) << 16;
    return v.f;
}

__device__ inline void atomicMinF(float* addr, float v) {
    if (v >= 0.f) atomicMin((int*)addr, __float_as_int(v));
    else          atomicMax((unsigned int*)addr, __float_as_uint(v));
}

// ---- pack (18 blocks) + scatter (rest), both LDS-free ----------------------
// BP layout: slot s holds 8 bf16 = B[k=kbase..kbase+7][col c]; the wave B-frag
// load for (ct, ks) is then 16B at BP + ((ct*KS+ks)*64 + lane)*8 — coalesced.
__global__ __launch_bounds__(256) void pack_scatter_kernel(
    const float* __restrict__ W1, const float* __restrict__ loop1,
    const float* __restrict__ W2, const float* __restrict__ loop2,
    ushortT* __restrict__ BP1, ushortT* __restrict__ BP2,
    const int* __restrict__ src, const int* __restrict__ dst,
    const int* __restrict__ et, int* __restrict__ cnt, int* __restrict__ eidx,
    int N, int E) {
    if (blockIdx.x < 18) {
        int g = (int)blockIdx.x * 256 + (int)threadIdx.x;  // 0..4607
        if (g < 3072) {
            // layer 1: 12 ct x 4 ks x 64 lanes
            int l = g & 63, ks = (g >> 6) & 3, ct = g >> 8;
            int c = ct * 16 + (l & 15);
            int mat = c >> 6, cc = c & 63;
            int kbase = ks * 32 + (l >> 4) * 8;
            ushortT* dstp = BP1 + (size_t)g * 8;
#pragma unroll
            for (int j = 0; j < 8; ++j) {
                int k = kbase + j;
                float v = (mat < 2) ? W1[((size_t)mat * 128 + k) * 64 + cc]
                                    : loop1[(size_t)k * 64 + cc];
                dstp[j] = f2bf(v);
            }
        } else {
            // layer 2: 12 ct x 2 ks x 64 lanes
            int s = g - 3072;
            int l = s & 63, ks = (s >> 6) & 1, ct = s >> 7;
            int c = ct * 16 + (l & 15);
            int mat = c >> 6, cc = c & 63;
            int kbase = ks * 32 + (l >> 4) * 8;
            ushortT* dstp = BP2 + (size_t)s * 8;
#pragma unroll
            for (int j = 0; j < 8; ++j) {
                int k = kbase + j;
                float v = (mat < 2) ? W2[((size_t)mat * 64 + k) * 64 + cc]
                                    : loop2[(size_t)k * 64 + cc];
                dstp[j] = f2bf(v);
            }
        }
        return;
    }
    // ---- scatter: 1024 edges/block, 4 per thread (batched atomics) ---------
    int e0 = ((int)blockIdx.x - 18) * 1024 + (int)threadIdx.x;
    int e1 = e0 + 256, e2 = e0 + 512, e3 = e0 + 768;
    bool a0 = e0 < E, a1 = e1 < E, a2 = e2 < E, a3 = e3 < E;
    int d0 = a0 ? dst[e0] : 0, d1 = a1 ? dst[e1] : 0;
    int d2 = a2 ? dst[e2] : 0, d3 = a3 ? dst[e3] : 0;
    int v0 = a0 ? (et[e0] * N + src[e0]) : 0;
    int v1 = a1 ? (et[e1] * N + src[e1]) : 0;
    int v2 = a2 ? (et[e2] * N + src[e2]) : 0;
    int v3 = a3 ? (et[e3] * N + src[e3]) : 0;
    int p0 = 0, p1 = 0, p2 = 0, p3 = 0;
    if (a0) p0 = atomicAdd(&cnt[d0], 1);
    if (a1) p1 = atomicAdd(&cnt[d1], 1);
    if (a2) p2 = atomicAdd(&cnt[d2], 1);
    if (a3) p3 = atomicAdd(&cnt[d3], 1);
    if (a0 && p0 < STRIDE) eidx[(size_t)d0 * STRIDE + p0] = v0;
    if (a1 && p1 < STRIDE) eidx[(size_t)d1 * STRIDE + p1] = v1;
    if (a2 && p2 < STRIDE) eidx[(size_t)d2 * STRIDE + p2] = v2;
    if (a3 && p3 < STRIDE) eidx[(size_t)d3 * STRIDE + p3] = v3;
}

// ---- gemm1 (MFMA): wave = 16 nodes x 192 cols, K=128, no LDS ---------------
__global__ __launch_bounds__(256) void gemm1_mfma(
    const float* __restrict__ x, const ushortT* __restrict__ BP1,
    const float* __restrict__ b1,
    ushortT* __restrict__ hrelb, ushortT* __restrict__ H1b, int N) {
    const int w = (int)threadIdx.x >> 6, lane = (int)threadIdx.x & 63;
    const int rowbase = ((int)blockIdx.x * 4 + w) * 16;
    const int m = lane & 15, quad = lane >> 4;
    const int nclamp = min(rowbase + m, N - 1);

    // A-frags: A[m][k = ks*32 + quad*8 + j] from x (fp32 -> bf16)
    short8 a[4];
    const float* xp = x + (size_t)nclamp * 128 + quad * 8;
#pragma unroll
    for (int ks = 0; ks < 4; ++ks) {
        float4 g0 = *(const float4*)(xp + ks * 32);
        float4 g1 = *(const float4*)(xp + ks * 32 + 4);
        a[ks][0] = (short)f2bf(g0.x); a[ks][1] = (short)f2bf(g0.y);
        a[ks][2] = (short)f2bf(g0.z); a[ks][3] = (short)f2bf(g0.w);
        a[ks][4] = (short)f2bf(g1.x); a[ks][5] = (short)f2bf(g1.y);
        a[ks][6] = (short)f2bf(g1.z); a[ks][7] = (short)f2bf(g1.w);
    }

    f32x4 acc[12];
#pragma unroll
    for (int ct = 0; ct < 12; ++ct) acc[ct] = (f32x4){0.f, 0.f, 0.f, 0.f};

#pragma unroll
    for (int ks = 0; ks < 4; ++ks) {
#pragma unroll
        for (int ct = 0; ct < 12; ++ct) {
            short8 b = *(const short8*)&BP1[((size_t)(ct * 4 + ks) * 64 + lane) * 8];
            acc[ct] = __builtin_amdgcn_mfma_f32_16x16x32_bf16(a[ks], b, acc[ct], 0, 0, 0);
        }
    }

    // C/D: col = lane&15, row = quad*4 + j
    const int node0 = rowbase + quad * 4;
#pragma unroll
    for (int ct = 0; ct < 12; ++ct) {
        int c = ct * 16 + m;
        int mat = c >> 6, cc = c & 63;
        float bias = (mat == 2) ? b1[cc] : 0.f;
#pragma unroll
        for (int j = 0; j < 4; ++j) {
            int n = node0 + j;
            if (n < N) {
                float v = acc[ct][j] + bias;
                if (mat < 2) hrelb[((size_t)mat * N + n) * 64 + cc] = f2bf(v);
                else         H1b[(size_t)n * 64 + cc] = f2bf(v);
            }
        }
    }
}

// ---- gemm2 (MFMA): wave = 16 nodes x 192 cols, K=64, bf16 A from H1b -------
__global__ __launch_bounds__(256) void gemm2_mfma(
    const ushortT* __restrict__ H1b, const ushortT* __restrict__ BP2,
    const float* __restrict__ b2,
    ushortT* __restrict__ hrel2b, ushortT* __restrict__ H2b, int N) {
    const int w = (int)threadIdx.x >> 6, lane = (int)threadIdx.x & 63;
    const int rowbase = ((int)blockIdx.x * 4 + w) * 16;
    const int m = lane & 15, quad = lane >> 4;
    const int nclamp = min(rowbase + m, N - 1);

    short8 a[2];
    const ushortT* hp = H1b + (size_t)nclamp * 64 + quad * 8;
    a[0] = *(const short8*)(hp);
    a[1] = *(const short8*)(hp + 32);

    f32x4 acc[12];
#pragma unroll
    for (int ct = 0; ct < 12; ++ct) acc[ct] = (f32x4){0.f, 0.f, 0.f, 0.f};

#pragma unroll
    for (int ks = 0; ks < 2; ++ks) {
#pragma unroll
        for (int ct = 0; ct < 12; ++ct) {
            short8 b = *(const short8*)&BP2[((size_t)(ct * 2 + ks) * 64 + lane) * 8];
            acc[ct] = __builtin_amdgcn_mfma_f32_16x16x32_bf16(a[ks], b, acc[ct], 0, 0, 0);
        }
    }

    const int node0 = rowbase + quad * 4;
#pragma unroll
    for (int ct = 0; ct < 12; ++ct) {
        int c = ct * 16 + m;
        int mat = c >> 6, cc = c & 63;
        float bias = (mat == 2) ? b2[cc] : 0.f;
#pragma unroll
        for (int j = 0; j < 4; ++j) {
            int n = node0 + j;
            if (n < N) {
                float v = acc[ct][j] + bias;
                if (mat < 2) hrel2b[((size_t)mat * N + n) * 64 + cc] = f2bf(v);
                else         H2b[(size_t)n * 64 + cc] = f2bf(v);
            }
        }
    }
}

// ---- agg1: wave per node, lane = channel, bf16 gather (8 outstanding) ------
__global__ void agg1_kernel(const ushortT* __restrict__ hrelb, const int* __restrict__ eidx,
                            const int* __restrict__ cnt, ushortT* __restrict__ H1b, int N) {
    int node = (int)blockIdx.x * 4 + ((int)threadIdx.x >> 6);
    if (node >= N) return;
    int lane = (int)threadIdx.x & 63;
    int deg = min(cnt[node], STRIDE);
    int my = (lane < deg) ? eidx[(size_t)node * STRIDE + lane] : 0;
    float acc = bf2f(H1b[(size_t)node * 64 + lane]);
    int j = 0;
    for (; j + 7 < deg; j += 8) {
        int id[8];
        float v[8];
#pragma unroll
        for (int q = 0; q < 8; ++q) id[q] = __shfl(my, j + q, 64);
#pragma unroll
        for (int q = 0; q < 8; ++q) v[q] = bf2f(hrelb[(size_t)id[q] * 64 + lane]);
        acc += ((v[0] + v[1]) + (v[2] + v[3])) + ((v[4] + v[5]) + (v[6] + v[7]));
    }
    for (; j < deg; ++j)
        acc += bf2f(hrelb[(size_t)__shfl(my, j, 64) * 64 + lane]);
    H1b[(size_t)node * 64 + lane] = f2bf(fmaxf(acc, 0.f));
}

// ---- K3: fused agg(layer2) + gemm(layer3, out=2), wave per node ------------
__global__ void k3_kernel(const ushortT* __restrict__ hrel2b, const ushortT* __restrict__ H2b,
                          const int* __restrict__ eidx, const int* __restrict__ cnt,
                          const float* __restrict__ W3, const float* __restrict__ loop3,
                          const float* __restrict__ b3,
                          float* __restrict__ hrel3, float* __restrict__ H3, int N) {
    int node = (int)blockIdx.x * 4 + ((int)threadIdx.x >> 6);
    if (node >= N) return;
    int lane = (int)threadIdx.x & 63;
    int deg = min(cnt[node], STRIDE);
    int my = (lane < deg) ? eidx[(size_t)node * STRIDE + lane] : 0;
    float acc = bf2f(H2b[(size_t)node * 64 + lane]);
    int j = 0;
    for (; j + 7 < deg; j += 8) {
        int id[8];
        float v[8];
#pragma unroll
        for (int q = 0; q < 8; ++q) id[q] = __shfl(my, j + q, 64);
#pragma unroll
        for (int q = 0; q < 8; ++q) v[q] = bf2f(hrel2b[(size_t)id[q] * 64 + lane]);
        acc += ((v[0] + v[1]) + (v[2] + v[3])) + ((v[4] + v[5]) + (v[6] + v[7]));
    }
    for (; j < deg; ++j)
        acc += bf2f(hrel2b[(size_t)__shfl(my, j, 64) * 64 + lane]);
    float xk = fmaxf(acc, 0.f);  // relu(layer-2 out), lane = k
    float p[6];
    p[0] = xk * W3[lane * 2 + 0];
    p[1] = xk * W3[lane * 2 + 1];
    p[2] = xk * W3[(64 + lane) * 2 + 0];
    p[3] = xk * W3[(64 + lane) * 2 + 1];
    p[4] = xk * loop3[lane * 2 + 0];
    p[5] = xk * loop3[lane * 2 + 1];
#pragma unroll
    for (int mm = 32; mm >= 1; mm >>= 1) {
#pragma unroll
        for (int q = 0; q < 6; ++q) p[q] += __shfl_xor(p[q], mm, 64);
    }
    if (lane == 0) {
        hrel3[(size_t)node * 2 + 0] = p[0];
        hrel3[(size_t)node * 2 + 1] = p[1];
        hrel3[((size_t)N + node) * 2 + 0] = p[2];
        hrel3[((size_t)N + node) * 2 + 1] = p[3];
        H3[(size_t)node * 2 + 0] = p[4] + b3[0];
        H3[(size_t)node * 2 + 1] = p[5] + b3[1];
    }
}

// ---- K4: layer-3 aggregation + global min ----------------------------------
__global__ void agg3min_kernel(const float* __restrict__ hrel3, const int* __restrict__ eidx,
                               const int* __restrict__ cnt, float* __restrict__ H3,
                               float* __restrict__ minval, int N) {
    int n = (int)blockIdx.x * 256 + (int)threadIdx.x;
    float v = 3.4e38f;
    if (n < N) {
        float a0 = H3[n * 2 + 0], a1 = H3[n * 2 + 1];
        int deg = min(cnt[n], STRIDE);
        const int* row = &eidx[(size_t)n * STRIDE];
        int j = 0;
        for (; j + 3 < deg; j += 4) {
            int i0 = row[j], i1 = row[j + 1], i2 = row[j + 2], i3 = row[j + 3];
            float2 q0 = *(const float2*)&hrel3[(size_t)i0 * 2];
            float2 q1 = *(const float2*)&hrel3[(size_t)i1 * 2];
            float2 q2 = *(const float2*)&hrel3[(size_t)i2 * 2];
            float2 q3 = *(const float2*)&hrel3[(size_t)i3 * 2];
            a0 += (q0.x + q1.x) + (q2.x + q3.x);
            a1 += (q0.y + q1.y) + (q2.y + q3.y);
        }
        for (; j < deg; ++j) {
            float2 q = *(const float2*)&hrel3[(size_t)row[j] * 2];
            a0 += q.x; a1 += q.y;
        }
        H3[n * 2 + 0] = a0;
        H3[n * 2 + 1] = a1;
        v = fminf(a0, a1);
    }
#pragma unroll
    for (int mm = 32; mm >= 1; mm >>= 1) v = fminf(v, __shfl_xor(v, mm, 64));
    __shared__ float s[4];
    if ((threadIdx.x & 63) == 0) s[threadIdx.x >> 6] = v;
    __syncthreads();
    if (threadIdx.x == 0)
        atomicMinF(minval, fminf(fminf(s[0], s[1]), fminf(s[2], s[3])));
}

__global__ void mask_kernel(const float* __restrict__ H3, const float* __restrict__ minval,
                            const int* __restrict__ cs, const int* __restrict__ ms,
                            float* __restrict__ out, int N) {
    int n = (int)blockIdx.x * 256 + (int)threadIdx.x;
    if (n >= N) return;
    float m = minval[0] - 1.0f;
    bool up = cs[n] >= ms[n] - 1;
    bool lo = cs[n] == 0;
    out[n * 2 + 0] = up ? m : H3[n * 2 + 0];
    out[n * 2 + 1] = lo ? m : H3[n * 2 + 1];
}

// ---------------------------------------------------------------------------
extern "C" void kernel_launch(void* const* d_in, const int* in_sizes, int n_in,
                              void* d_out, int out_size, void* d_ws, size_t ws_size,
                              hipStream_t stream) {
    const float* x     = (const float*)d_in[0];
    const int* src     = (const int*)d_in[1];
    const int* dst     = (const int*)d_in[2];
    const int* etypes  = (const int*)d_in[3];
    const int* cellsz  = (const int*)d_in[4];
    const int* maxsz   = (const int*)d_in[5];
    const float* W1    = (const float*)d_in[6];
    const float* loop1 = (const float*)d_in[7];
    const float* b1    = (const float*)d_in[8];
    const float* W2    = (const float*)d_in[9];
    const float* loop2 = (const float*)d_in[10];
    const float* b2    = (const float*)d_in[11];
    const float* W3    = (const float*)d_in[12];
    const float* loop3 = (const float*)d_in[13];
    const float* b3    = (const float*)d_in[14];
    float* out = (float*)d_out;

    const int N = in_sizes[0] / 128;  // 50000
    const int E = in_sizes[1];        // 800000

    char* p = (char*)d_ws;
    auto alloc = [&](size_t bytes) -> void* {
        void* r = (void*)p;
        p += ((bytes + 255) / 256) * 256;
        return r;
    };
    ushortT* hrelb  = (ushortT*)alloc((size_t)2 * N * 64 * 2);  // 12.8 MB bf16
    ushortT* H1b    = (ushortT*)alloc((size_t)N * 64 * 2);      //  6.4 MB bf16
    ushortT* hrel2b = (ushortT*)alloc((size_t)2 * N * 64 * 2);  // 12.8 MB bf16
    ushortT* H2b    = (ushortT*)alloc((size_t)N * 64 * 2);      //  6.4 MB bf16
    float* hrel3    = (float*)alloc((size_t)2 * N * 2 * 4);
    float* H3       = (float*)alloc((size_t)N * 2 * 4);
    int* cnt        = (int*)alloc((size_t)N * 4);
    int* eidx       = (int*)alloc((size_t)N * STRIDE * 4);      // 12.8 MB
    ushortT* BP1    = (ushortT*)alloc((size_t)3072 * 8 * 2);    // 48 KB frag-packed
    ushortT* BP2    = (ushortT*)alloc((size_t)1536 * 8 * 2);    // 24 KB
    float* minval   = (float*)alloc(4);
    (void)ws_size; (void)n_in; (void)out_size;

    const int NB_N   = (N + 255) / 256;      // 196
    const int NTILES = (N + 63) / 64;        // 782
    const int NB_W   = (N + 3) / 4;          // 12500
    const int NB_SC  = (E + 1023) / 1024;    // 782

    hipMemsetAsync(cnt, 0, (size_t)N * 4, stream);
    hipMemsetAsync(minval, 0x7f, 4, stream);  // 0x7f7f7f7f = 3.39e38

    // weight fragment-pack (18 blocks) + bucket scatter, one lean launch
    pack_scatter_kernel<<<18 + NB_SC, 256, 0, stream>>>(
        W1, loop1, W2, loop2, BP1, BP2, src, dst, etypes, cnt, eidx, N, E);

    // layer-1 GEMM (MFMA)
    gemm1_mfma<<<NTILES, 256, 0, stream>>>(x, BP1, b1, hrelb, H1b, N);

    // layer-1 aggregation: wave per node
    agg1_kernel<<<NB_W, 256, 0, stream>>>(hrelb, eidx, cnt, H1b, N);

    // layer-2 GEMM (MFMA)
    gemm2_mfma<<<NTILES, 256, 0, stream>>>(H1b, BP2, b2, hrel2b, H2b, N);

    // fused agg(layer2) + gemm(layer3)
    k3_kernel<<<NB_W, 256, 0, stream>>>(hrel2b, H2b, eidx, cnt, W3, loop3, b3,
                                        hrel3, H3, N);

    // layer-3 aggregation + global min, then mask
    agg3min_kernel<<<NB_N, 256, 0, stream>>>(hrel3, eidx, cnt, H3, minval, N);
    mask_kernel<<<NB_N, 256, 0, stream>>>(H3, minval, cellsz, maxsz, out, N);
}

// Round 8
// 218.472 us; speedup vs baseline: 1.3520x; 1.1811x over previous
//
#include <hip/hip_runtime.h>

// ---------------------------------------------------------------------------
// RelGraphConv x3 + action mask, MI355X (gfx950) — round 8
// R7 post-mortem: FAILED — intra-launch producer/consumer race: gemm1 blocks
// read BP1 packed by sibling blocks of the SAME launch (dispatch order
// undefined, G16). Fix: pack+init is its own tiny pre-launch (also zeroes
// bincnt/minval, dropping both memset dispatches). K1 keeps phaseA || gemm1
// (independent). Rest identical to R7's two-phase binned scatter design.
// ---------------------------------------------------------------------------

#define STRIDE 64    // bucket capacity; P(deg>=64) astronomically small
#define BINCAP 2560  // records per bin; mean 2048, sigma~45 -> 11 sigma margin

typedef unsigned short ushortT;
typedef __attribute__((ext_vector_type(8))) short short8;   // 8 bf16 (4 VGPRs)
typedef __attribute__((ext_vector_type(4))) float f32x4;    // MFMA C/D

__device__ inline ushortT f2bf(float f) {
    union { float f; unsigned u; } v; v.f = f;
    unsigned r = v.u + 0x7FFFu + ((v.u >> 16) & 1u);   // RNE
    return (ushortT)(r >> 16);
}
__device__ inline float bf2f(ushortT h) {
    union { unsigned u; float f; } v; v.u = ((unsigned)h) << 16;
    return v.f;
}

__device__ inline void atomicMinF(float* addr, float v) {
    if (v >= 0.f) atomicMin((int*)addr, __float_as_int(v));
    else          atomicMax((unsigned int*)addr, __float_as_uint(v));
}

// ---- K0: weight pack + bincnt/minval init (tiny, runs before everything) ---
__global__ __launch_bounds__(256) void pack_init_kernel(
    const float* __restrict__ W1, const float* __restrict__ loop1,
    const float* __restrict__ W2, const float* __restrict__ loop2,
    ushortT* __restrict__ BP1, ushortT* __restrict__ BP2,
    int* __restrict__ bincnt, float* __restrict__ minval, int NBINS) {
    int g = (int)blockIdx.x * 256 + (int)threadIdx.x;  // 0..4607
    if (g < NBINS) bincnt[g] = 0;
    if (g == 0) *(int*)minval = 0x7f7f7f7f;            // 3.39e38
    if (g < 3072) {
        // layer 1: 12 ct x 4 ks x 64 lanes
        int l = g & 63, ks = (g >> 6) & 3, ct = g >> 8;
        int c = ct * 16 + (l & 15);
        int mat = c >> 6, cc = c & 63;
        int kbase = ks * 32 + (l >> 4) * 8;
        ushortT* dstp = BP1 + (size_t)g * 8;
#pragma unroll
        for (int j = 0; j < 8; ++j) {
            int k = kbase + j;
            float v = (mat < 2) ? W1[((size_t)mat * 128 + k) * 64 + cc]
                                : loop1[(size_t)k * 64 + cc];
            dstp[j] = f2bf(v);
        }
    } else {
        // layer 2: 12 ct x 2 ks x 64 lanes
        int s = g - 3072;
        int l = s & 63, ks = (s >> 6) & 1, ct = s >> 7;
        int c = ct * 16 + (l & 15);
        int mat = c >> 6, cc = c & 63;
        int kbase = ks * 32 + (l >> 4) * 8;
        ushortT* dstp = BP2 + (size_t)s * 8;
#pragma unroll
        for (int j = 0; j < 8; ++j) {
            int k = kbase + j;
            float v = (mat < 2) ? W2[((size_t)mat * 64 + k) * 64 + cc]
                                : loop2[(size_t)k * 64 + cc];
            dstp[j] = f2bf(v);
        }
    }
}

// ---- K1: phaseA-binning [0,NBA) | gemm1 [NBA, NBA+NTILES) ------------------
__global__ __launch_bounds__(256) void k1_kernel(
    const float* __restrict__ x, const ushortT* __restrict__ BP1,
    const float* __restrict__ b1,
    ushortT* __restrict__ hrelb, ushortT* __restrict__ H1b,
    const int* __restrict__ src, const int* __restrict__ dst,
    const int* __restrict__ et, int* __restrict__ bincnt, int2* __restrict__ binbuf,
    int N, int E, int NBINS, int NBA) {
    __shared__ int hist[512];
    __shared__ int gbase[512];
    __shared__ ushortT rnk[4096];

    const int t = (int)threadIdx.x;

    if ((int)blockIdx.x < NBA) {
        // ---- phase A: bin 4096 edges ---------------------------------------
        for (int i = t; i < NBINS; i += 256) hist[i] = 0;
        __syncthreads();
        const int base = (int)blockIdx.x * 4096;
#pragma unroll
        for (int i = 0; i < 16; ++i) {
            int e = base + t + i * 256;
            if (e < E) {
                int bb = dst[e] >> 7;
                rnk[t + i * 256] = (ushortT)atomicAdd(&hist[bb], 1);
            }
        }
        __syncthreads();
        for (int i = t; i < NBINS; i += 256) {
            int h = hist[i];
            gbase[i] = h ? atomicAdd(&bincnt[i], h) : 0;
        }
        __syncthreads();
#pragma unroll
        for (int i = 0; i < 16; ++i) {
            int e = base + t + i * 256;
            if (e < E) {
                int dd = dst[e];
                int bb = dd >> 7;
                int v = et[e] * N + src[e];
                int pos = gbase[bb] + (int)rnk[t + i * 256];
                if (pos < BINCAP)
                    binbuf[(size_t)bb * BINCAP + pos] = make_int2(dd, v);
            }
        }
        return;
    }
    // ---- gemm1 (MFMA): wave = 16 nodes x 192 cols, K=128, no LDS use -------
    const int w = t >> 6, lane = t & 63;
    const int rowbase = (((int)blockIdx.x - NBA) * 4 + w) * 16;
    const int m = lane & 15, quad = lane >> 4;
    const int nclamp = min(rowbase + m, N - 1);

    short8 a[4];
    const float* xp = x + (size_t)nclamp * 128 + quad * 8;
#pragma unroll
    for (int ks = 0; ks < 4; ++ks) {
        float4 g0 = *(const float4*)(xp + ks * 32);
        float4 g1 = *(const float4*)(xp + ks * 32 + 4);
        a[ks][0] = (short)f2bf(g0.x); a[ks][1] = (short)f2bf(g0.y);
        a[ks][2] = (short)f2bf(g0.z); a[ks][3] = (short)f2bf(g0.w);
        a[ks][4] = (short)f2bf(g1.x); a[ks][5] = (short)f2bf(g1.y);
        a[ks][6] = (short)f2bf(g1.z); a[ks][7] = (short)f2bf(g1.w);
    }

    f32x4 acc[12];
#pragma unroll
    for (int ct = 0; ct < 12; ++ct) acc[ct] = (f32x4){0.f, 0.f, 0.f, 0.f};

#pragma unroll
    for (int ks = 0; ks < 4; ++ks) {
#pragma unroll
        for (int ct = 0; ct < 12; ++ct) {
            short8 b = *(const short8*)&BP1[((size_t)(ct * 4 + ks) * 64 + lane) * 8];
            acc[ct] = __builtin_amdgcn_mfma_f32_16x16x32_bf16(a[ks], b, acc[ct], 0, 0, 0);
        }
    }

    const int node0 = rowbase + quad * 4;
#pragma unroll
    for (int ct = 0; ct < 12; ++ct) {
        int c = ct * 16 + m;
        int mat = c >> 6, cc = c & 63;
        float bias = (mat == 2) ? b1[cc] : 0.f;
#pragma unroll
        for (int j = 0; j < 4; ++j) {
            int n = node0 + j;
            if (n < N) {
                float v = acc[ct][j] + bias;
                if (mat < 2) hrelb[((size_t)mat * N + n) * 64 + cc] = f2bf(v);
                else         H1b[(size_t)n * 64 + cc] = f2bf(v);
            }
        }
    }
}

// ---- K2: phase B — block per bin, LDS counting, local eidx writes ----------
__global__ __launch_bounds__(256) void phaseB_kernel(
    const int* __restrict__ bincnt, const int2* __restrict__ binbuf,
    int* __restrict__ cnt, int* __restrict__ eidx, int N) {
    __shared__ int lcnt[128];
    const int b = (int)blockIdx.x;
    const int t = (int)threadIdx.x;
    if (t < 128) lcnt[t] = 0;
    __syncthreads();
    const int cb = min(bincnt[b], BINCAP);
    const int2* buf = binbuf + (size_t)b * BINCAP;
    for (int i = t; i < cb; i += 256) {
        int2 rec = buf[i];
        int r = atomicAdd(&lcnt[rec.x & 127], 1);
        if (r < STRIDE) eidx[(size_t)rec.x * STRIDE + r] = rec.y;
    }
    __syncthreads();
    int node = b * 128 + t;
    if (t < 128 && node < N) cnt[node] = min(lcnt[t], STRIDE);
}

// ---- agg1: wave per node, lane = channel, bf16 gather (8 outstanding) ------
__global__ void agg1_kernel(const ushortT* __restrict__ hrelb, const int* __restrict__ eidx,
                            const int* __restrict__ cnt, ushortT* __restrict__ H1b, int N) {
    int node = (int)blockIdx.x * 4 + ((int)threadIdx.x >> 6);
    if (node >= N) return;
    int lane = (int)threadIdx.x & 63;
    int deg = cnt[node];
    int my = (lane < deg) ? eidx[(size_t)node * STRIDE + lane] : 0;
    float acc = bf2f(H1b[(size_t)node * 64 + lane]);
    int j = 0;
    for (; j + 7 < deg; j += 8) {
        int id[8];
        float v[8];
#pragma unroll
        for (int q = 0; q < 8; ++q) id[q] = __shfl(my, j + q, 64);
#pragma unroll
        for (int q = 0; q < 8; ++q) v[q] = bf2f(hrelb[(size_t)id[q] * 64 + lane]);
        acc += ((v[0] + v[1]) + (v[2] + v[3])) + ((v[4] + v[5]) + (v[6] + v[7]));
    }
    for (; j < deg; ++j)
        acc += bf2f(hrelb[(size_t)__shfl(my, j, 64) * 64 + lane]);
    H1b[(size_t)node * 64 + lane] = f2bf(fmaxf(acc, 0.f));
}

// ---- gemm2 (MFMA): wave = 16 nodes x 192 cols, K=64, bf16 A from H1b -------
__global__ __launch_bounds__(256) void gemm2_mfma(
    const ushortT* __restrict__ H1b, const ushortT* __restrict__ BP2,
    const float* __restrict__ b2,
    ushortT* __restrict__ hrel2b, ushortT* __restrict__ H2b, int N) {
    const int w = (int)threadIdx.x >> 6, lane = (int)threadIdx.x & 63;
    const int rowbase = ((int)blockIdx.x * 4 + w) * 16;
    const int m = lane & 15, quad = lane >> 4;
    const int nclamp = min(rowbase + m, N - 1);

    short8 a[2];
    const ushortT* hp = H1b + (size_t)nclamp * 64 + quad * 8;
    a[0] = *(const short8*)(hp);
    a[1] = *(const short8*)(hp + 32);

    f32x4 acc[12];
#pragma unroll
    for (int ct = 0; ct < 12; ++ct) acc[ct] = (f32x4){0.f, 0.f, 0.f, 0.f};

#pragma unroll
    for (int ks = 0; ks < 2; ++ks) {
#pragma unroll
        for (int ct = 0; ct < 12; ++ct) {
            short8 b = *(const short8*)&BP2[((size_t)(ct * 2 + ks) * 64 + lane) * 8];
            acc[ct] = __builtin_amdgcn_mfma_f32_16x16x32_bf16(a[ks], b, acc[ct], 0, 0, 0);
        }
    }

    const int node0 = rowbase + quad * 4;
#pragma unroll
    for (int ct = 0; ct < 12; ++ct) {
        int c = ct * 16 + m;
        int mat = c >> 6, cc = c & 63;
        float bias = (mat == 2) ? b2[cc] : 0.f;
#pragma unroll
        for (int j = 0; j < 4; ++j) {
            int n = node0 + j;
            if (n < N) {
                float v = acc[ct][j] + bias;
                if (mat < 2) hrel2b[((size_t)mat * N + n) * 64 + cc] = f2bf(v);
                else         H2b[(size_t)n * 64 + cc] = f2bf(v);
            }
        }
    }
}

// ---- K3: fused agg(layer2) + gemm(layer3, out=2), wave per node ------------
__global__ void k3_kernel(const ushortT* __restrict__ hrel2b, const ushortT* __restrict__ H2b,
                          const int* __restrict__ eidx, const int* __restrict__ cnt,
                          const float* __restrict__ W3, const float* __restrict__ loop3,
                          const float* __restrict__ b3,
                          float* __restrict__ hrel3, float* __restrict__ H3, int N) {
    int node = (int)blockIdx.x * 4 + ((int)threadIdx.x >> 6);
    if (node >= N) return;
    int lane = (int)threadIdx.x & 63;
    int deg = cnt[node];
    int my = (lane < deg) ? eidx[(size_t)node * STRIDE + lane] : 0;
    float acc = bf2f(H2b[(size_t)node * 64 + lane]);
    int j = 0;
    for (; j + 7 < deg; j += 8) {
        int id[8];
        float v[8];
#pragma unroll
        for (int q = 0; q < 8; ++q) id[q] = __shfl(my, j + q, 64);
#pragma unroll
        for (int q = 0; q < 8; ++q) v[q] = bf2f(hrel2b[(size_t)id[q] * 64 + lane]);
        acc += ((v[0] + v[1]) + (v[2] + v[3])) + ((v[4] + v[5]) + (v[6] + v[7]));
    }
    for (; j < deg; ++j)
        acc += bf2f(hrel2b[(size_t)__shfl(my, j, 64) * 64 + lane]);
    float xk = fmaxf(acc, 0.f);  // relu(layer-2 out), lane = k
    float p[6];
    p[0] = xk * W3[lane * 2 + 0];
    p[1] = xk * W3[lane * 2 + 1];
    p[2] = xk * W3[(64 + lane) * 2 + 0];
    p[3] = xk * W3[(64 + lane) * 2 + 1];
    p[4] = xk * loop3[lane * 2 + 0];
    p[5] = xk * loop3[lane * 2 + 1];
#pragma unroll
    for (int mm = 32; mm >= 1; mm >>= 1) {
#pragma unroll
        for (int q = 0; q < 6; ++q) p[q] += __shfl_xor(p[q], mm, 64);
    }
    if (lane == 0) {
        hrel3[(size_t)node * 2 + 0] = p[0];
        hrel3[(size_t)node * 2 + 1] = p[1];
        hrel3[((size_t)N + node) * 2 + 0] = p[2];
        hrel3[((size_t)N + node) * 2 + 1] = p[3];
        H3[(size_t)node * 2 + 0] = p[4] + b3[0];
        H3[(size_t)node * 2 + 1] = p[5] + b3[1];
    }
}

// ---- K4: layer-3 aggregation + global min ----------------------------------
__global__ void agg3min_kernel(const float* __restrict__ hrel3, const int* __restrict__ eidx,
                               const int* __restrict__ cnt, float* __restrict__ H3,
                               float* __restrict__ minval, int N) {
    int n = (int)blockIdx.x * 256 + (int)threadIdx.x;
    float v = 3.4e38f;
    if (n < N) {
        float a0 = H3[n * 2 + 0], a1 = H3[n * 2 + 1];
        int deg = cnt[n];
        const int* row = &eidx[(size_t)n * STRIDE];
        int j = 0;
        for (; j + 3 < deg; j += 4) {
            int i0 = row[j], i1 = row[j + 1], i2 = row[j + 2], i3 = row[j + 3];
            float2 q0 = *(const float2*)&hrel3[(size_t)i0 * 2];
            float2 q1 = *(const float2*)&hrel3[(size_t)i1 * 2];
            float2 q2 = *(const float2*)&hrel3[(size_t)i2 * 2];
            float2 q3 = *(const float2*)&hrel3[(size_t)i3 * 2];
            a0 += (q0.x + q1.x) + (q2.x + q3.x);
            a1 += (q0.y + q1.y) + (q2.y + q3.y);
        }
        for (; j < deg; ++j) {
            float2 q = *(const float2*)&hrel3[(size_t)row[j] * 2];
            a0 += q.x; a1 += q.y;
        }
        H3[n * 2 + 0] = a0;
        H3[n * 2 + 1] = a1;
        v = fminf(a0, a1);
    }
#pragma unroll
    for (int mm = 32; mm >= 1; mm >>= 1) v = fminf(v, __shfl_xor(v, mm, 64));
    __shared__ float s[4];
    if ((threadIdx.x & 63) == 0) s[threadIdx.x >> 6] = v;
    __syncthreads();
    if (threadIdx.x == 0)
        atomicMinF(minval, fminf(fminf(s[0], s[1]), fminf(s[2], s[3])));
}

__global__ void mask_kernel(const float* __restrict__ H3, const float* __restrict__ minval,
                            const int* __restrict__ cs, const int* __restrict__ ms,
                            float* __restrict__ out, int N) {
    int n = (int)blockIdx.x * 256 + (int)threadIdx.x;
    if (n >= N) return;
    float m = minval[0] - 1.0f;
    bool up = cs[n] >= ms[n] - 1;
    bool lo = cs[n] == 0;
    out[n * 2 + 0] = up ? m : H3[n * 2 + 0];
    out[n * 2 + 1] = lo ? m : H3[n * 2 + 1];
}

// ---------------------------------------------------------------------------
extern "C" void kernel_launch(void* const* d_in, const int* in_sizes, int n_in,
                              void* d_out, int out_size, void* d_ws, size_t ws_size,
                              hipStream_t stream) {
    const float* x     = (const float*)d_in[0];
    const int* src     = (const int*)d_in[1];
    const int* dst     = (const int*)d_in[2];
    const int* etypes  = (const int*)d_in[3];
    const int* cellsz  = (const int*)d_in[4];
    const int* maxsz   = (const int*)d_in[5];
    const float* W1    = (const float*)d_in[6];
    const float* loop1 = (const float*)d_in[7];
    const float* b1    = (const float*)d_in[8];
    const float* W2    = (const float*)d_in[9];
    const float* loop2 = (const float*)d_in[10];
    const float* b2    = (const float*)d_in[11];
    const float* W3    = (const float*)d_in[12];
    const float* loop3 = (const float*)d_in[13];
    const float* b3    = (const float*)d_in[14];
    float* out = (float*)d_out;

    const int N = in_sizes[0] / 128;  // 50000
    const int E = in_sizes[1];        // 800000

    char* p = (char*)d_ws;
    auto alloc = [&](size_t bytes) -> void* {
        void* r = (void*)p;
        p += ((bytes + 255) / 256) * 256;
        return r;
    };
    ushortT* hrelb  = (ushortT*)alloc((size_t)2 * N * 64 * 2);  // 12.8 MB bf16
    ushortT* H1b    = (ushortT*)alloc((size_t)N * 64 * 2);      //  6.4 MB bf16
    ushortT* hrel2b = (ushortT*)alloc((size_t)2 * N * 64 * 2);  // 12.8 MB bf16
    ushortT* H2b    = (ushortT*)alloc((size_t)N * 64 * 2);      //  6.4 MB bf16
    float* hrel3    = (float*)alloc((size_t)2 * N * 2 * 4);
    float* H3       = (float*)alloc((size_t)N * 2 * 4);
    int* cnt        = (int*)alloc((size_t)N * 4);
    int* eidx       = (int*)alloc((size_t)N * STRIDE * 4);      // 12.8 MB
    ushortT* BP1    = (ushortT*)alloc((size_t)3072 * 8 * 2);    // 48 KB frag-packed
    ushortT* BP2    = (ushortT*)alloc((size_t)1536 * 8 * 2);    // 24 KB
    float* minval   = (float*)alloc(4);

    const int NBINS = (N + 127) >> 7;                           // 391
    int* bincnt     = (int*)alloc((size_t)NBINS * 4);
    int2* binbuf    = (int2*)alloc((size_t)NBINS * BINCAP * 8); // 8.0 MB
    (void)ws_size; (void)n_in; (void)out_size;

    const int NB_N   = (N + 255) / 256;      // 196
    const int NTILES = (N + 63) / 64;        // 782
    const int NB_W   = (N + 3) / 4;          // 12500
    const int NBA    = (E + 4095) / 4096;    // 196 phase-A blocks

    // K0: weight pack + bincnt/minval init (separate launch: producer ordering)
    pack_init_kernel<<<18, 256, 0, stream>>>(
        W1, loop1, W2, loop2, BP1, BP2, bincnt, minval, NBINS);

    // K1: phase-A binning || layer-1 MFMA GEMM (independent halves)
    k1_kernel<<<NBA + NTILES, 256, 0, stream>>>(
        x, BP1, b1, hrelb, H1b,
        src, dst, etypes, bincnt, binbuf, N, E, NBINS, NBA);

    // K2: phase B — bin-local scatter into eidx buckets + cnt
    phaseB_kernel<<<NBINS, 256, 0, stream>>>(bincnt, binbuf, cnt, eidx, N);

    // layer-1 aggregation: wave per node
    agg1_kernel<<<NB_W, 256, 0, stream>>>(hrelb, eidx, cnt, H1b, N);

    // layer-2 GEMM (MFMA)
    gemm2_mfma<<<NTILES, 256, 0, stream>>>(H1b, BP2, b2, hrel2b, H2b, N);

    // fused agg(layer2) + gemm(layer3)
    k3_kernel<<<NB_W, 256, 0, stream>>>(hrel2b, H2b, eidx, cnt, W3, loop3, b3,
                                        hrel3, H3, N);

    // layer-3 aggregation + global min, then mask
    agg3min_kernel<<<NB_N, 256, 0, stream>>>(hrel3, eidx, cnt, H3, minval, N);
    mask_kernel<<<NB_N, 256, 0, stream>>>(H3, minval, cellsz, maxsz, out, N);
}